// Round 11
// baseline (599.579 us; speedup 1.0000x reference)
//
#include <hip/hip_runtime.h>
#include <hip/hip_bf16.h>

// GCN 3-layer + MLP head.
// Round 10 (fix: vector-element reference bind in agg epilogue).
// Carry activations as pre-split bf16 hi/lo pairs between ops:
//  - producers (agg1, gemm1 epilogue, agg2) emit hi/lo ONCE (truncation split, ~5 ops)
//  - all GEMMs stage A via pure 16B loads -> LDS (no per-tile fp32->bf16 VALU work)
//  - +2q LDS rotate spreads staging-write banks
// Aggregations gather fp32 (x, h2, h3): agg1 is at the L3-gather floor.

#define WG 256

typedef __attribute__((ext_vector_type(4))) float f32x4;
typedef __attribute__((ext_vector_type(8))) short bf16x8;
typedef __attribute__((ext_vector_type(4))) unsigned short u16x4;
typedef __attribute__((ext_vector_type(8))) unsigned short u16x8;

__device__ inline unsigned short f2bf(float v) {
    union { float f; unsigned u; } c; c.f = v;
    unsigned r = (c.u + 0x7fff + ((c.u >> 16) & 1)) >> 16;   // RNE
    return (unsigned short)r;
}
__device__ inline float bf2f(unsigned short h) {
    union { unsigned u; float f; } c; c.u = ((unsigned)h) << 16;
    return c.f;
}
// cheap truncation split: v = hi + lo + eps, |eps| <= 2^-16 |v|
__device__ inline void splitbf(float v, unsigned short& h, unsigned short& l) {
    unsigned u = __float_as_uint(v);
    h = (unsigned short)(u >> 16);
    float hf = __uint_as_float(u & 0xffff0000u);
    l = (unsigned short)(__float_as_uint(v - hf) >> 16);
}

// ---------------- graph build ----------------

__global__ void count_kernel(const int* __restrict__ row, int* __restrict__ cnt, int E) {
    int e = blockIdx.x * blockDim.x + threadIdx.x;
    if (e < E) atomicAdd(&cnt[row[e]], 1);
}

__global__ void dis_kernel(const int* __restrict__ cnt, float* __restrict__ dis, int n) {
    int i = blockIdx.x * blockDim.x + threadIdx.x;
    if (i < n) {
        float d = (float)(cnt[i] + 1);
        dis[i] = 1.0f / sqrtf(d);
    }
}

// exclusive scan of (cnt[i]+1) -> rowstart[0..n]; single block, wave-shuffle based
__global__ __launch_bounds__(1024) void scan_kernel(const int* __restrict__ cnt,
                                                    int* __restrict__ rowstart, int n) {
    __shared__ int wsum[16];
    __shared__ int carry;
    const int tid = threadIdx.x;
    const int lane = tid & 63, wv = tid >> 6;
    if (tid == 0) { rowstart[0] = 0; carry = 0; }
    __syncthreads();
    for (int base = 0; base < n; base += 1024) {
        int i = base + tid;
        int v = (i < n) ? (cnt[i] + 1) : 0;
        int s = v;
        #pragma unroll
        for (int off = 1; off < 64; off <<= 1) {
            int t = __shfl_up(s, off);
            if (lane >= off) s += t;
        }
        if (lane == 63) wsum[wv] = s;
        __syncthreads();
        if (wv == 0 && lane < 16) {
            int ws = wsum[lane];
            int t = ws;
            #pragma unroll
            for (int off = 1; off < 16; off <<= 1) {
                int u = __shfl_up(t, off);
                if (lane >= off) t += u;
            }
            wsum[lane] = t - ws;       // exclusive wave offset
        }
        __syncthreads();
        int tp = carry;
        if (i < n) rowstart[i + 1] = tp + wsum[wv] + s;
        __syncthreads();
        if (tid == 1023) carry = tp + wsum[15] + s;
        __syncthreads();
    }
}

__global__ void selfloop_kernel(const int* __restrict__ rowstart, const float* __restrict__ dis,
                                int* __restrict__ edge_dst, float* __restrict__ edge_norm,
                                int* __restrict__ fill, int n) {
    int i = blockIdx.x * blockDim.x + threadIdx.x;
    if (i < n) {
        int p = rowstart[i];
        edge_dst[p] = i;
        float d = dis[i];
        edge_norm[p] = d * d;
        fill[i] = 1;
    }
}

__global__ void scatter_kernel(const int* __restrict__ row, const int* __restrict__ col,
                               const int* __restrict__ rowstart, const float* __restrict__ dis,
                               int* __restrict__ edge_dst, float* __restrict__ edge_norm,
                               int* __restrict__ fill, int E) {
    int e = blockIdx.x * blockDim.x + threadIdx.x;
    if (e < E) {
        int r = row[e], c = col[e];
        int pos = rowstart[r] + atomicAdd(&fill[r], 1);
        edge_dst[pos] = c;
        edge_norm[pos] = dis[r] * dis[c];
    }
}

// ---------------- weight conversion: W[K,N] fp32 -> frag layout [Kpad/8][Npad][8] bf16 hi/lo ----------------

__global__ void convB_kernel(const float* __restrict__ W,
                             unsigned short* __restrict__ bth, unsigned short* __restrict__ btl,
                             int K, int N, int Kpad, int Npad) {
    int idx = blockIdx.x * blockDim.x + threadIdx.x;
    int total = (Kpad / 8) * Npad * 8;
    if (idx >= total) return;
    int i = idx & 7;
    int rest = idx >> 3;
    int n = rest % Npad;
    int qg = rest / Npad;
    int k = qg * 8 + i;
    float v = (k < K && n < N) ? W[k * N + n] : 0.f;
    unsigned short h = f2bf(v);                 // RNE hi (one-time, best accuracy)
    unsigned short l = f2bf(v - bf2f(h));
    bth[idx] = h;
    btl[idx] = l;
}

// ---------------- split-A MFMA GEMM ----------------
// A given as two bf16 arrays Ahg/Alg, row-major [M][Kpad] (zero-padded K).
// C = (Ah+Al) @ (Bh+Bl) via 3 MFMA passes. Tile 128x64, 4 waves, K-step 32.
// Output: fp32 (Cf) OR split hi/lo (Ch/Cl), both row stride = Npad.

__global__ __launch_bounds__(256) void mfma_gemm_sp(const unsigned short* __restrict__ Ahg,
                                                    const unsigned short* __restrict__ Alg,
                                                    const unsigned short* __restrict__ Bth,
                                                    const unsigned short* __restrict__ Btl,
                                                    float* __restrict__ Cf,
                                                    unsigned short* __restrict__ Ch,
                                                    unsigned short* __restrict__ Cl,
                                                    const float* __restrict__ bias,
                                                    int M, int Kpad, int Npad, int Nbias, int dorelu) {
    __shared__ unsigned short Ah[4 * 128 * 8];   // [q][r'][8], r' = (r + 2q) & 127
    __shared__ unsigned short Al[4 * 128 * 8];
    const int tid  = threadIdx.x;
    const int lane = tid & 63;
    const int wid  = tid >> 6;
    const int wm   = (wid >> 1) * 64;
    const int wn   = (wid & 1) * 32;
    const int m0   = blockIdx.y * 128;
    const int n0   = blockIdx.x * 64;
    const int q    = lane >> 4;
    const int lr   = lane & 15;

    f32x4 acc[4][2];
    #pragma unroll
    for (int i = 0; i < 4; ++i)
        #pragma unroll
        for (int j = 0; j < 2; ++j) {
            f32x4 z = {0.f, 0.f, 0.f, 0.f};
            acc[i][j] = z;
        }

    u16x8 rg[4];

    auto load_tile = [&](int k0) {
        #pragma unroll
        for (int it = 0; it < 4; ++it) {
            int lin = (it & 1) * 256 + tid;      // 0..511
            int r   = lin >> 2;                  // 0..127
            int qq  = lin & 3;                   // 0..3
            const unsigned short* src = (it < 2) ? Ahg : Alg;
            int row = m0 + r;
            u16x8 v = {0, 0, 0, 0, 0, 0, 0, 0};
            if (row < M) v = *(const u16x8*)(src + (size_t)row * Kpad + k0 + qq * 8);
            rg[it] = v;
        }
    };

    auto write_stage = [&]() {
        #pragma unroll
        for (int it = 0; it < 4; ++it) {
            int lin = (it & 1) * 256 + tid;
            int r   = lin >> 2;
            int qq  = lin & 3;
            unsigned short* dst = (it < 2) ? Ah : Al;
            int rs = (r + 2 * qq) & 127;         // bank rotate
            *(u16x8*)(dst + (qq * 128 + rs) * 8) = rg[it];
        }
    };

    load_tile(0);
    const int nk = Kpad >> 5;
    for (int t = 0; t < nk; ++t) {
        if (t) __syncthreads();
        write_stage();
        __syncthreads();
        if (t + 1 < nk) load_tile((t + 1) * 32);

        bf16x8 ah[4], al[4];
        #pragma unroll
        for (int mf = 0; mf < 4; ++mf) {
            int row = wm + mf * 16 + lr;
            int rs  = (row + 2 * q) & 127;
            int off = (q * 128 + rs) * 8;
            ah[mf] = *(const bf16x8*)(Ah + off);
            al[mf] = *(const bf16x8*)(Al + off);
        }
        bf16x8 bh[2], bl[2];
        int qg = t * 4 + q;
        #pragma unroll
        for (int nf = 0; nf < 2; ++nf) {
            int n = n0 + wn + nf * 16 + lr;
            size_t coff = ((size_t)qg * Npad + n) * 8;
            bh[nf] = *(const bf16x8*)(Bth + coff);
            bl[nf] = *(const bf16x8*)(Btl + coff);
        }
        #pragma unroll
        for (int mf = 0; mf < 4; ++mf)
            #pragma unroll
            for (int nf = 0; nf < 2; ++nf)
                acc[mf][nf] = __builtin_amdgcn_mfma_f32_16x16x32_bf16(ah[mf], bh[nf], acc[mf][nf], 0, 0, 0);
        #pragma unroll
        for (int mf = 0; mf < 4; ++mf)
            #pragma unroll
            for (int nf = 0; nf < 2; ++nf)
                acc[mf][nf] = __builtin_amdgcn_mfma_f32_16x16x32_bf16(ah[mf], bl[nf], acc[mf][nf], 0, 0, 0);
        #pragma unroll
        for (int mf = 0; mf < 4; ++mf)
            #pragma unroll
            for (int nf = 0; nf < 2; ++nf)
                acc[mf][nf] = __builtin_amdgcn_mfma_f32_16x16x32_bf16(al[mf], bh[nf], acc[mf][nf], 0, 0, 0);
    }

    #pragma unroll
    for (int nf = 0; nf < 2; ++nf) {
        int col = n0 + wn + nf * 16 + lr;
        float bb = (bias != nullptr && col < Nbias) ? bias[col] : 0.f;
        #pragma unroll
        for (int mf = 0; mf < 4; ++mf) {
            int row_base = m0 + wm + mf * 16 + (lane >> 4) * 4;
            #pragma unroll
            for (int r = 0; r < 4; ++r) {
                int row = row_base + r;
                if (row >= M) continue;
                float v = acc[mf][nf][r] + bb;
                if (dorelu) v = fmaxf(v, 0.f);
                size_t o = (size_t)row * Npad + col;
                if (Cf != nullptr) {
                    Cf[o] = v;
                } else {
                    unsigned short h, l;
                    splitbf(v, h, l);
                    Ch[o] = h;
                    Cl[o] = l;
                }
            }
        }
    }
}

// ---------------- CSR gather aggregation ----------------
// R4 = float4s per source row (src stride = R4*4 floats); EPW = edges in parallel
// per wave (R4*EPW == 64). One wave per node, 4 nodes per 256-thread block.
// Output either fp32 (outf) or split bf16 hi/lo (outh/outl), stride in elems.

template <int R4, int EPW>
__global__ __launch_bounds__(256) void agg_kernel(const float* __restrict__ src,
                                                  const int* __restrict__ rowstart,
                                                  const int* __restrict__ edge_dst,
                                                  const float* __restrict__ edge_norm,
                                                  const float* __restrict__ bias,
                                                  float* __restrict__ outf,
                                                  unsigned short* __restrict__ outh,
                                                  unsigned short* __restrict__ outl,
                                                  int out_stride, int fout, int dorelu,
                                                  int nnodes) {
    const int wid  = threadIdx.x >> 6;
    const int node = blockIdx.x * 4 + wid;
    if (node >= nnodes) return;
    const int lane = threadIdx.x & 63;
    const int g    = lane / R4;
    const int lg   = lane % R4;
    const int start = rowstart[node], end = rowstart[node + 1];
    const f32x4* s4 = (const f32x4*)src;
    f32x4 acc = {0.f, 0.f, 0.f, 0.f};

    for (int base = start; base < end; base += 64) {
        int nb = end - base;
        if (nb > 64) nb = 64;
        int ge = base + lane;
        int idx = (lane < nb) ? edge_dst[ge] : 0;
        float w = (lane < nb) ? edge_norm[ge] : 0.f;
        int iters = (nb + EPW - 1) / EPW;
        int j = 0;
        for (; j + 4 <= iters; j += 4) {
            int c0 = __shfl(idx, (j + 0) * EPW + g); float w0 = __shfl(w, (j + 0) * EPW + g);
            int c1 = __shfl(idx, (j + 1) * EPW + g); float w1 = __shfl(w, (j + 1) * EPW + g);
            int c2 = __shfl(idx, (j + 2) * EPW + g); float w2 = __shfl(w, (j + 2) * EPW + g);
            int c3 = __shfl(idx, (j + 3) * EPW + g); float w3 = __shfl(w, (j + 3) * EPW + g);
            f32x4 v0 = s4[(size_t)c0 * R4 + lg];
            f32x4 v1 = s4[(size_t)c1 * R4 + lg];
            f32x4 v2 = s4[(size_t)c2 * R4 + lg];
            f32x4 v3 = s4[(size_t)c3 * R4 + lg];
            acc += v0 * w0;
            acc += v1 * w1;
            acc += v2 * w2;
            acc += v3 * w3;
        }
        for (; j < iters; ++j) {
            int sl = j * EPW + g;
            int c = __shfl(idx, sl); float w0 = __shfl(w, sl);
            f32x4 v = s4[(size_t)c * R4 + lg];
            acc += v * w0;
        }
    }

    // cross-group reduction (groups hold different edges of the same node)
    #pragma unroll
    for (int d = R4; d < 64; d <<= 1) {
        #pragma unroll
        for (int k = 0; k < 4; ++k) acc[k] += __shfl_xor(acc[k], d);
    }

    if (g == 0) {
        int f0 = lg * 4;
        if (f0 < out_stride) {
            f32x4 v = acc;
            if (bias != nullptr) {
                #pragma unroll
                for (int e = 0; e < 4; ++e) {
                    int f = f0 + e;
                    if (f < fout) {
                        float t = v[e] + bias[f];
                        if (dorelu) t = fmaxf(t, 0.f);
                        v[e] = t;
                    }
                }
            }
            size_t o = (size_t)node * out_stride + f0;
            if (outh != nullptr) {
                u16x4 hv, lv;
                #pragma unroll
                for (int e = 0; e < 4; ++e) {
                    unsigned short hh, ll;
                    splitbf(v[e], hh, ll);
                    hv[e] = hh;
                    lv[e] = ll;
                }
                *(u16x4*)(outh + o) = hv;
                *(u16x4*)(outl + o) = lv;
            } else {
                *(f32x4*)(outf + o) = v;
            }
        }
    }
}

// ---------------- fused final MLP ----------------

__global__ void final_kernel(const float* __restrict__ a3,
                             const float* __restrict__ Wf1, const float* __restrict__ bf1,
                             const float* __restrict__ Wf2, const float* __restrict__ bf2,
                             float* __restrict__ out, int n, int C, int H) {
    int i = blockIdx.x * blockDim.x + threadIdx.x;
    if (i >= n) return;
    const float* xr = a3 + (size_t)i * C;
    float hbuf[16];
    for (int j = 0; j < H; ++j) hbuf[j] = bf1[j];
    for (int k = 0; k < C; ++k) {
        float xv = xr[k];
        for (int j = 0; j < H; ++j) hbuf[j] += xv * Wf1[k * H + j];
    }
    float o = bf2[0];
    for (int j = 0; j < H; ++j) o += hbuf[j] * Wf2[j];
    out[i] = o;
}

// ---------------- launch ----------------

extern "C" void kernel_launch(void* const* d_in, const int* in_sizes, int n_in,
                              void* d_out, int out_size, void* d_ws, size_t ws_size,
                              hipStream_t stream) {
    const float* x   = (const float*)d_in[0];
    const int*   ei  = (const int*)d_in[1];
    const float* W1  = (const float*)d_in[2];
    const float* b1  = (const float*)d_in[3];
    const float* W2  = (const float*)d_in[4];
    const float* b2  = (const float*)d_in[5];
    const float* W3  = (const float*)d_in[6];
    const float* b3  = (const float*)d_in[7];
    const float* Wf1 = (const float*)d_in[8];
    const float* bf1 = (const float*)d_in[9];
    const float* Wf2 = (const float*)d_in[10];
    const float* bf2 = (const float*)d_in[11];
    float* out = (float*)d_out;

    const int N    = out_size;                 // 50000
    const int E    = in_sizes[1] / 2;          // 800000
    const int IN_C = in_sizes[0] / N;          // 256
    const int H1   = in_sizes[3];              // 300
    const int H2   = in_sizes[5];              // 100
    const int OUTC = in_sizes[7];              // 32
    const int F1   = in_sizes[9];              // 16
    const int EL   = E + N;

    const int KP1 = 256, NP1 = 320;            // layer1: K=256 (=IN_C), N=300 (pad 320 = KP2)
    const int KP2 = 320, NP2 = 128;            // layer2: K=300, N=100 (pad 128 = KP3)
    const int KP3 = 128, NP3 = 64;             // layer3: K=100, N=32

    const int* row = ei;
    const int* col = ei + E;

    size_t off = 0;
    auto alloc = [&](size_t bytes) {
        size_t o = off;
        off += (bytes + 255) & ~(size_t)255;
        return o;
    };
    char* ws = (char*)d_ws;
    int*   cnt      = (int*)  (ws + alloc((size_t)N * 4));
    int*   fill     = (int*)  (ws + alloc((size_t)N * 4));
    float* dis      = (float*)(ws + alloc((size_t)N * 4));
    int*   rowstart = (int*)  (ws + alloc((size_t)(N + 1) * 4));
    int*   edge_dst = (int*)  (ws + alloc((size_t)EL * 4));
    float* edge_nrm = (float*)(ws + alloc((size_t)EL * 4));
    unsigned short* Bt1h = (unsigned short*)(ws + alloc((size_t)(KP1/8) * NP1 * 8 * 2));
    unsigned short* Bt1l = (unsigned short*)(ws + alloc((size_t)(KP1/8) * NP1 * 8 * 2));
    unsigned short* Bt2h = (unsigned short*)(ws + alloc((size_t)(KP2/8) * NP2 * 8 * 2));
    unsigned short* Bt2l = (unsigned short*)(ws + alloc((size_t)(KP2/8) * NP2 * 8 * 2));
    unsigned short* Bt3h = (unsigned short*)(ws + alloc((size_t)(KP3/8) * NP3 * 8 * 2));
    unsigned short* Bt3l = (unsigned short*)(ws + alloc((size_t)(KP3/8) * NP3 * 8 * 2));
    // bufP (51.2 MB): phase 1: agg_xh+agg_xl; phase 2: h2 + a2h + a2l; phase 3: h3 + a3
    char* bufP = ws + alloc((size_t)N * KP1 * 4);
    // bufQ (64 MB): a1h + a1l
    char* bufQ = ws + alloc((size_t)N * KP2 * 4);

    unsigned short* agg_xh = (unsigned short*)bufP;                             // [N,256] bf16
    unsigned short* agg_xl = (unsigned short*)(bufP + (size_t)N * KP1 * 2);     // [N,256] bf16
    unsigned short* a1h    = (unsigned short*)bufQ;                             // [N,320] bf16
    unsigned short* a1l    = (unsigned short*)(bufQ + (size_t)N * KP2 * 2);     // [N,320] bf16
    float*          h2     = (float*)bufP;                                      // [N,128] fp32 (agg_x dead)
    unsigned short* a2h    = (unsigned short*)(bufP + (size_t)N * NP2 * 4);     // [N,128] bf16
    unsigned short* a2l    = (unsigned short*)(bufP + (size_t)N * NP2 * 4 + (size_t)N * KP3 * 2);
    float*          h3     = (float*)bufP;                                      // [N,64] fp32 (h2 dead)
    float*          a3     = (float*)(bufP + (size_t)N * NP3 * 4);              // [N,32] fp32

    const int gN = (N + WG - 1) / WG;
    const int gE = (E + WG - 1) / WG;
    const int gAgg = (N + 3) / 4;

    // --- build CSR ---
    hipMemsetAsync(cnt, 0, (size_t)N * 4, stream);
    count_kernel<<<gE, WG, 0, stream>>>(row, cnt, E);
    dis_kernel<<<gN, WG, 0, stream>>>(cnt, dis, N);
    scan_kernel<<<1, 1024, 0, stream>>>(cnt, rowstart, N);
    selfloop_kernel<<<gN, WG, 0, stream>>>(rowstart, dis, edge_dst, edge_nrm, fill, N);
    scatter_kernel<<<gE, WG, 0, stream>>>(row, col, rowstart, dis, edge_dst, edge_nrm, fill, E);

    // --- convert weights ---
    {
        int t1 = (KP1/8) * NP1 * 8;
        convB_kernel<<<(t1 + WG - 1) / WG, WG, 0, stream>>>(W1, Bt1h, Bt1l, IN_C, H1, KP1, NP1);
        int t2 = (KP2/8) * NP2 * 8;
        convB_kernel<<<(t2 + WG - 1) / WG, WG, 0, stream>>>(W2, Bt2h, Bt2l, H1, H2, KP2, NP2);
        int t3 = (KP3/8) * NP3 * 8;
        convB_kernel<<<(t3 + WG - 1) / WG, WG, 0, stream>>>(W3, Bt3h, Bt3l, H2, OUTC, KP3, NP3);
    }

    const int MB = (N + 127) / 128;

    // --- layer 1: agg X -> split bf16; GEMM (split in, split out, fused bias+relu) ---
    agg_kernel<64, 1><<<gAgg, WG, 0, stream>>>(x, rowstart, edge_dst, edge_nrm,
                                               nullptr, nullptr, agg_xh, agg_xl,
                                               KP1, KP1, 0, N);
    mfma_gemm_sp<<<dim3(NP1 / 64, MB), 256, 0, stream>>>(agg_xh, agg_xl, Bt1h, Bt1l,
                                                         nullptr, a1h, a1l, b1,
                                                         N, KP1, NP1, H1, 1);
    // --- layer 2: GEMM (split in, fp32 out); agg h2 -> split bf16 (bias+relu fused) ---
    mfma_gemm_sp<<<dim3(NP2 / 64, MB), 256, 0, stream>>>(a1h, a1l, Bt2h, Bt2l,
                                                         h2, nullptr, nullptr, nullptr,
                                                         N, KP2, NP2, 0, 0);
    agg_kernel<32, 2><<<gAgg, WG, 0, stream>>>(h2, rowstart, edge_dst, edge_nrm,
                                               b2, nullptr, a2h, a2l,
                                               KP3, H2, 1, N);
    // --- layer 3: GEMM (split in, fp32 out); agg h3 -> fp32 a3 ---
    mfma_gemm_sp<<<dim3(NP3 / 64, MB), 256, 0, stream>>>(a2h, a2l, Bt3h, Bt3l,
                                                         h3, nullptr, nullptr, nullptr,
                                                         N, KP3, NP3, 0, 0);
    agg_kernel<16, 4><<<gAgg, WG, 0, stream>>>(h3, rowstart, edge_dst, edge_nrm,
                                               b3, a3, nullptr, nullptr,
                                               OUTC, OUTC, 1, N);
    // --- final MLP ---
    final_kernel<<<gN, WG, 0, stream>>>(a3, Wf1, bf1, Wf2, bf2, out, N, OUTC, F1);
}